// Round 3
// baseline (4527.748 us; speedup 1.0000x reference)
//
#include <hip/hip_runtime.h>
#include <math.h>

#define D 64
#define MIN_NORM 1e-15f

#define RCP(x)  __builtin_amdgcn_rcpf(x)
#define RSQ(x)  __builtin_amdgcn_rsqf(x)

// ---------------- DPP butterfly within 16-lane rows ----------------
// After the 4 steps every lane in each 16-lane group holds the group sum.
template <int CTRL>
__device__ __forceinline__ float dpp_sum_step(float v) {
    int iv = __builtin_bit_cast(int, v);
    int sh = __builtin_amdgcn_update_dpp(0, iv, CTRL, 0xf, 0xf, true);
    return v + __builtin_bit_cast(float, sh);
}
#define DPP_XOR1  0xB1   // quad_perm [1,0,3,2]
#define DPP_XOR2  0x4E   // quad_perm [2,3,0,1]
#define DPP_HMIR  0x141  // row_half_mirror (pairs 8-lane halves)
#define DPP_MIR   0x140  // row_mirror (pairs 16-lane halves)

__device__ __forceinline__ float row16_sum(float v) {
    v = dpp_sum_step<DPP_XOR1>(v);
    v = dpp_sum_step<DPP_XOR2>(v);
    v = dpp_sum_step<DPP_HMIR>(v);
    v = dpp_sum_step<DPP_MIR>(v);
    return v;
}

// ---------------- fast transcendentals (args >= 0) ----------------

__device__ __forceinline__ float fast_tanh_pos(float x) {
    float t = __expf(-2.0f * x);
    return (1.0f - t) * RCP(1.0f + t);
}

__device__ __forceinline__ float fast_atanh(float x) {
    return 0.5f * __logf((1.0f + x) * RCP(1.0f - x));
}

// ---------------- RGAT edge kernel: 16 lanes per edge, 4 edges per wave ----
// All Mobius-chain vectors are linear combos of (he, te, re); one 4-step DPP
// butterfly over the 6-entry Gram matrix replaces all wave reductions.

__global__ __launch_bounds__(256) void rgat_edge_kernel(
    const float* __restrict__ ent, const float* __restrict__ rel,
    const int* __restrict__ head, const int* __restrict__ tail,
    const int* __restrict__ etype,
    float* __restrict__ sums, float* __restrict__ cnt, int n_edges)
{
    int e = blockIdx.x * 16 + (threadIdx.x >> 4);
    if (e >= n_edges) return;
    int sub = threadIdx.x & 15;

    int h = head[e];
    int t = tail[e];
    int r = etype[e] - 1;

    float4 he = ((const float4*)(ent + (size_t)h * D))[sub];
    float4 te = ((const float4*)(ent + (size_t)t * D))[sub];
    float4 re = ((const float4*)(rel + (size_t)r * D))[sub];

    // Gram matrix partials (4 dims per lane)
    float v0 = he.x*he.x + he.y*he.y + he.z*he.z + he.w*he.w;
    float v1 = te.x*te.x + te.y*te.y + te.z*te.z + te.w*te.w;
    float v2 = re.x*re.x + re.y*re.y + re.z*re.z + re.w*re.w;
    float v3 = he.x*te.x + he.y*te.y + he.z*te.z + he.w*te.w;
    float v4 = he.x*re.x + he.y*re.y + he.z*re.z + he.w*re.w;
    float v5 = te.x*re.x + te.y*re.y + te.z*re.z + te.w*re.w;
    float HE2 = row16_sum(v0);
    float TE2 = row16_sum(v1);
    float RE2 = row16_sum(v2);
    float HT  = row16_sum(v3);
    float HR  = row16_sum(v4);
    float TR  = row16_sum(v5);

    // ---- scalar chain (uniform within each 16-lane group) ----
    // ricci coefficient: 1e-7 / max(||te+re||, 1e-12)
    float S2 = TE2 + 2.0f * TR + RE2;
    float ricci_k = 1e-7f * RSQ(fmaxf(S2, 1e-24f));

    // hh = expmap0(he) = a*he
    float HE2g = fmaxf(HE2, 1e-30f);
    float rNhe = RSQ(HE2g);
    float Nhe  = HE2g * rNhe;                 // = max(||he||, 1e-15)
    float a = fast_tanh_pos(Nhe) * rNhe;
    float HH2 = a * a * HE2;
    float mterm = fmaxf(1.0f - HH2, MIN_NORM);   // = 2/lam
    float rmterm = RCP(mterm);                   // = lam/2

    // wt = b*te ; wr = c*re
    float TE2g = fmaxf(TE2, 1e-30f);
    float rNte = RSQ(TE2g);
    float b = fast_tanh_pos(TE2g * rNte * rmterm) * rNte;
    float RE2g = fmaxf(RE2, 1e-30f);
    float rNre = RSQ(RE2g);
    float c = fast_tanh_pos(RE2g * rNre * rmterm) * rNre;

    // ht = mobius_add(hh, wt) = p1*he + q1*te
    float y2t = b * b * TE2, xyt = a * b * HT;
    float A1 = 1.0f + 2.0f * xyt + y2t, B1 = 1.0f - HH2;
    float r_d1 = RCP(fmaxf(1.0f + 2.0f * xyt + HH2 * y2t, MIN_NORM));
    float p1 = A1 * a * r_d1, q1 = B1 * b * r_d1;
    float HT2 = fmaxf((A1*A1*HH2 + 2.0f*A1*B1*xyt + B1*B1*y2t) * r_d1 * r_d1, 0.0f);

    // hr = mobius_add(hh, wr) = p2*he + q2*re
    float y2r = c * c * RE2, xyr = a * c * HR;
    float A2 = 1.0f + 2.0f * xyr + y2r, B2 = 1.0f - HH2;
    float r_d2 = RCP(fmaxf(1.0f + 2.0f * xyr + HH2 * y2r, MIN_NORM));
    float p2 = A2 * a * r_d2, q2 = B2 * c * r_d2;
    float HR2 = fmaxf((A2*A2*HH2 + 2.0f*A2*B2*xyr + B2*B2*y2r) * r_d2 * r_d2, 0.0f);

    // res = mobius_add(ht, hr) = al*he + be*te + ga*re
    float xy3 = p1*p2*HE2 + p1*q2*HR + q1*p2*HT + q1*q2*TR;
    float A3 = 1.0f + 2.0f * xy3 + HR2, B3 = 1.0f - HT2;
    float r_d3 = RCP(fmaxf(1.0f + 2.0f * xy3 + HT2 * HR2, MIN_NORM));
    float al = (A3 * p1 + B3 * p2) * r_d3;
    float be = A3 * q1 * r_d3;
    float ga = B3 * q2 * r_d3;
    float R2 = fmaxf((A3*A3*HT2 + 2.0f*A3*B3*xy3 + B3*B3*HR2) * r_d3 * r_d3, 0.0f);

    // project to ball
    float R2g = fmaxf(R2, 1e-30f);
    float rNr = RSQ(R2g);
    float Nr  = R2g * rNr;
    const float maxn = 1.0f - 1e-3f;
    if (Nr > maxn) {
        float s = maxn * rNr;
        al *= s; be *= s; ga *= s;
        R2 = maxn * maxn;
    }

    // sub = mobius_add(-hh, res) = sh*he + st*te + sr*re
    float dhr = a * (al * HE2 + be * HT + ga * HR);
    float xy4 = -dhr;
    float A4 = 1.0f + 2.0f * xy4 + R2, B4 = 1.0f - HH2;
    float r_d4 = RCP(fmaxf(1.0f + 2.0f * xy4 + HH2 * R2, MIN_NORM));
    float sh = (-A4 * a + B4 * al) * r_d4;
    float st = B4 * be * r_d4;
    float sr = B4 * ga * r_d4;
    float SUB2 = fmaxf((A4*A4*HH2 + 2.0f*A4*B4*xy4 + B4*B4*R2) * r_d4 * r_d4, 0.0f);

    float SUB2g = fmaxf(SUB2, 1e-30f);
    float rNsub = RSQ(SUB2g);
    float Nsub  = SUB2g * rNsub;
    float k = mterm * fast_atanh(fminf(Nsub, 1.0f - 1e-5f)) * rNsub;

    // outv = relu(kh*he + kt*te + kr*re)
    float kh = k * sh;
    float kt = k * st + ricci_k;
    float kr = k * sr + ricci_k;

    float* dst = sums + (size_t)h * D + sub * 4;
    atomicAdd(dst + 0, fmaxf(kh*he.x + kt*te.x + kr*re.x, 0.0f));
    atomicAdd(dst + 1, fmaxf(kh*he.y + kt*te.y + kr*re.y, 0.0f));
    atomicAdd(dst + 2, fmaxf(kh*he.z + kt*te.z + kr*re.z, 0.0f));
    atomicAdd(dst + 3, fmaxf(kh*he.w + kt*te.w + kr*re.w, 0.0f));
    if (sub == 0) atomicAdd(&cnt[h], 1.0f);
}

// ---------------- per-entity finalize: mean -> l2norm -> residual ----------------

__global__ __launch_bounds__(256) void finalize_hop_kernel(
    const float* __restrict__ sums, const float* __restrict__ cnt,
    const float* __restrict__ prev_res,
    float* __restrict__ ent_out, float* __restrict__ res_out, int n_ent)
{
    int row = blockIdx.x * 16 + (threadIdx.x >> 4);
    if (row >= n_ent) return;
    int sub = threadIdx.x & 15;

    float rc = RCP(fmaxf(cnt[row], 1.0f));
    float4 m = ((const float4*)(sums + (size_t)row * D))[sub];
    m.x *= rc; m.y *= rc; m.z *= rc; m.w *= rc;

    float M2 = row16_sum(m.x*m.x + m.y*m.y + m.z*m.z + m.w*m.w);
    float rn = RSQ(fmaxf(M2, 1e-24f));   // 1/max(||m||,1e-12)
    float4 v = make_float4(m.x*rn, m.y*rn, m.z*rn, m.w*rn);

    ((float4*)(ent_out + (size_t)row * D))[sub] = v;
    float4 p = ((const float4*)(prev_res + (size_t)row * D))[sub];
    ((float4*)(res_out + (size_t)row * D))[sub] =
        make_float4(0.5f*p.x + v.x, 0.5f*p.y + v.y, 0.5f*p.z + v.z, 0.5f*p.w + v.w);
}

// ---------------- GCN: concat init, COO spmm (atomic), add ----------------

__global__ void concat_init_kernel(const float4* __restrict__ u,
                                   const float4* __restrict__ res,
                                   float4* __restrict__ bufA,
                                   float4* __restrict__ out,
                                   int user4, int total4)
{
    int i = blockIdx.x * blockDim.x + threadIdx.x;
    if (i >= total4) return;
    float4 v = (i < user4) ? u[i] : res[i - user4];
    bufA[i] = v;
    out[i] = v;
}

__global__ __launch_bounds__(256) void spmm_kernel(
    const float* __restrict__ val, const int* __restrict__ row,
    const int* __restrict__ col,
    const float* __restrict__ cur, float* __restrict__ nxt, int nnz)
{
    int e = blockIdx.x * 16 + (threadIdx.x >> 4);
    if (e >= nnz) return;
    int sub = threadIdx.x & 15;
    int r = row[e];
    int c = col[e];
    float v = val[e];
    float4 x = ((const float4*)(cur + (size_t)c * D))[sub];
    float* dst = nxt + (size_t)r * D + sub * 4;
    atomicAdd(dst + 0, v * x.x);
    atomicAdd(dst + 1, v * x.y);
    atomicAdd(dst + 2, v * x.z);
    atomicAdd(dst + 3, v * x.w);
}

__global__ void add_kernel(float4* __restrict__ out, const float4* __restrict__ b, int n)
{
    int i = blockIdx.x * blockDim.x + threadIdx.x;
    if (i >= n) return;
    float4 o = out[i];
    float4 a = b[i];
    o.x += a.x; o.y += a.y; o.z += a.z; o.w += a.w;
    out[i] = o;
}

// ---------------- launch ----------------

extern "C" void kernel_launch(void* const* d_in, const int* in_sizes, int n_in,
                              void* d_out, int out_size, void* d_ws, size_t ws_size,
                              hipStream_t stream)
{
    const float* uE      = (const float*)d_in[0];
    const float* eE      = (const float*)d_in[1];
    const float* rE      = (const float*)d_in[2];
    const float* adj_val = (const float*)d_in[3];
    const int*   e_head  = (const int*)d_in[4];
    const int*   e_tail  = (const int*)d_in[5];
    const int*   e_type  = (const int*)d_in[6];
    const int*   a_row   = (const int*)d_in[7];
    const int*   a_col   = (const int*)d_in[8];

    const int n_user  = in_sizes[0] / D;   // 100000
    const int n_ent   = in_sizes[1] / D;   // 200000
    const int nnz     = in_sizes[3];       // 2000000
    const int n_edges = in_sizes[4];       // 500000
    const int n_rows  = out_size / D;      // 150000 (users + items)

    float* ws = (float*)d_ws;
    const size_t entElems = (size_t)n_ent * D;           // 12.8M floats
    float* sums    = ws;                                  // later: GCN bufA
    float* cnt     = ws + entElems;                       // adjacent -> single memset
    float* ent1    = ws + entElems + n_ent;               // later: GCN bufB
    float* ent_res = ws + 2 * entElems + n_ent;

    float* out = (float*)d_out;

    const int edge_blocks = (n_edges + 15) / 16;
    const int ent_blocks  = (n_ent + 15) / 16;
    const int nnz_blocks  = (nnz + 15) / 16;

    // ---- RGAT hop 1 (input: eEmbeds) ----
    hipMemsetAsync(sums, 0, (entElems + n_ent) * sizeof(float), stream);
    rgat_edge_kernel<<<edge_blocks, 256, 0, stream>>>(eE, rE, e_head, e_tail, e_type,
                                                      sums, cnt, n_edges);
    // ent1 = l2norm(mean); ent_res = 0.5*eEmbeds + ent1
    finalize_hop_kernel<<<ent_blocks, 256, 0, stream>>>(sums, cnt, eE, ent1, ent_res, n_ent);

    // ---- RGAT hop 2 (input: ent1) ----
    hipMemsetAsync(sums, 0, (entElems + n_ent) * sizeof(float), stream);
    rgat_edge_kernel<<<edge_blocks, 256, 0, stream>>>(ent1, rE, e_head, e_tail, e_type,
                                                      sums, cnt, n_edges);
    // ent_res = 0.5*ent_res + l2norm(mean)
    finalize_hop_kernel<<<ent_blocks, 256, 0, stream>>>(sums, cnt, ent_res, ent1, ent_res, n_ent);

    // ---- GCN ----
    float* bufA = sums;   // reuse
    float* bufB = ent1;

    const int total4 = n_rows * (D / 4);     // 2.4M float4
    const int user4  = n_user * (D / 4);

    concat_init_kernel<<<(total4 + 255) / 256, 256, 0, stream>>>(
        (const float4*)uE, (const float4*)ent_res, (float4*)bufA, (float4*)out,
        user4, total4);

    // layer 1: bufB = spmm(adj, bufA); out += bufB
    hipMemsetAsync(bufB, 0, (size_t)n_rows * D * sizeof(float), stream);
    spmm_kernel<<<nnz_blocks, 256, 0, stream>>>(adj_val, a_row, a_col, bufA, bufB, nnz);
    add_kernel<<<(total4 + 255) / 256, 256, 0, stream>>>((float4*)out, (const float4*)bufB, total4);

    // layer 2: bufA = spmm(adj, bufB); out += bufA
    hipMemsetAsync(bufA, 0, (size_t)n_rows * D * sizeof(float), stream);
    spmm_kernel<<<nnz_blocks, 256, 0, stream>>>(adj_val, a_row, a_col, bufB, bufA, nnz);
    add_kernel<<<(total4 + 255) / 256, 256, 0, stream>>>((float4*)out, (const float4*)bufA, total4);
}

// Round 5
// 1398.294 us; speedup vs baseline: 3.2381x; 3.2381x over previous
//
#include <hip/hip_runtime.h>
#include <math.h>

#define D 64
#define MIN_NORM 1e-15f

#define RCP(x)  __builtin_amdgcn_rcpf(x)
#define RSQ(x)  __builtin_amdgcn_rsqf(x)

// ---------------- DPP butterfly within 16-lane rows ----------------
template <int CTRL>
__device__ __forceinline__ float dpp_sum_step(float v) {
    int iv = __builtin_bit_cast(int, v);
    int sh = __builtin_amdgcn_update_dpp(0, iv, CTRL, 0xf, 0xf, true);
    return v + __builtin_bit_cast(float, sh);
}
#define DPP_XOR1  0xB1   // quad_perm [1,0,3,2]
#define DPP_XOR2  0x4E   // quad_perm [2,3,0,1]
#define DPP_HMIR  0x141  // row_half_mirror
#define DPP_MIR   0x140  // row_mirror

__device__ __forceinline__ float row16_sum(float v) {
    v = dpp_sum_step<DPP_XOR1>(v);
    v = dpp_sum_step<DPP_XOR2>(v);
    v = dpp_sum_step<DPP_HMIR>(v);
    v = dpp_sum_step<DPP_MIR>(v);
    return v;
}

// ---------------- fast transcendentals (args >= 0) ----------------

__device__ __forceinline__ float fast_tanh_pos(float x) {
    float t = __expf(-2.0f * x);
    return (1.0f - t) * RCP(1.0f + t);
}

__device__ __forceinline__ float fast_atanh(float x) {
    return 0.5f * __logf((1.0f + x) * RCP(1.0f - x));
}

// ---------------- RGAT edge kernel: 16 lanes/edge, STRIDED dim layout ------
// dim = c*16 + sub  (component c of lane sub). Gram reduction is dim-order
// agnostic; loads and atomic stores are one full contiguous 64B cacheline
// per instruction per edge. No transpose, no write inflation.

__global__ __launch_bounds__(256) void rgat_edge_kernel(
    const float* __restrict__ ent, const float* __restrict__ rel,
    const int* __restrict__ head, const int* __restrict__ tail,
    const int* __restrict__ etype,
    float* __restrict__ sums, float* __restrict__ cnt, int n_edges)
{
    int e = blockIdx.x * 16 + (threadIdx.x >> 4);
    int ec = min(e, n_edges - 1);          // clamp; no early return (DPP below)
    bool active = (e < n_edges);
    int sub = threadIdx.x & 15;

    int h = head[ec];
    int t = tail[ec];
    int r = etype[ec] - 1;

    const float* hp = ent + (size_t)h * D + sub;
    const float* tp = ent + (size_t)t * D + sub;
    const float* rp = rel + (size_t)r * D + sub;
    float hex = hp[0], hey = hp[16], hez = hp[32], hew = hp[48];
    float tex = tp[0], tey = tp[16], tez = tp[32], tew = tp[48];
    float rex = rp[0], rey = rp[16], rez = rp[32], rew = rp[48];

    // Gram matrix partials (4 dims per lane)
    float v0 = hex*hex + hey*hey + hez*hez + hew*hew;
    float v1 = tex*tex + tey*tey + tez*tez + tew*tew;
    float v2 = rex*rex + rey*rey + rez*rez + rew*rew;
    float v3 = hex*tex + hey*tey + hez*tez + hew*tew;
    float v4 = hex*rex + hey*rey + hez*rez + hew*rew;
    float v5 = tex*rex + tey*rey + tez*rez + tew*rew;
    float HE2 = row16_sum(v0);
    float TE2 = row16_sum(v1);
    float RE2 = row16_sum(v2);
    float HT  = row16_sum(v3);
    float HR  = row16_sum(v4);
    float TR  = row16_sum(v5);

    // ---- scalar chain (uniform within each 16-lane group) ----
    float S2 = TE2 + 2.0f * TR + RE2;
    float ricci_k = 1e-7f * RSQ(fmaxf(S2, 1e-24f));

    float HE2g = fmaxf(HE2, 1e-30f);
    float rNhe = RSQ(HE2g);
    float Nhe  = HE2g * rNhe;
    float a = fast_tanh_pos(Nhe) * rNhe;
    float HH2 = a * a * HE2;
    float mterm = fmaxf(1.0f - HH2, MIN_NORM);   // = 2/lam
    float rmterm = RCP(mterm);

    float TE2g = fmaxf(TE2, 1e-30f);
    float rNte = RSQ(TE2g);
    float b = fast_tanh_pos(TE2g * rNte * rmterm) * rNte;
    float RE2g = fmaxf(RE2, 1e-30f);
    float rNre = RSQ(RE2g);
    float c = fast_tanh_pos(RE2g * rNre * rmterm) * rNre;

    float y2t = b * b * TE2, xyt = a * b * HT;
    float A1 = 1.0f + 2.0f * xyt + y2t, B1 = 1.0f - HH2;
    float r_d1 = RCP(fmaxf(1.0f + 2.0f * xyt + HH2 * y2t, MIN_NORM));
    float p1 = A1 * a * r_d1, q1 = B1 * b * r_d1;
    float HT2 = fmaxf((A1*A1*HH2 + 2.0f*A1*B1*xyt + B1*B1*y2t) * r_d1 * r_d1, 0.0f);

    float y2r = c * c * RE2, xyr = a * c * HR;
    float A2 = 1.0f + 2.0f * xyr + y2r, B2 = 1.0f - HH2;
    float r_d2 = RCP(fmaxf(1.0f + 2.0f * xyr + HH2 * y2r, MIN_NORM));
    float p2 = A2 * a * r_d2, q2 = B2 * c * r_d2;
    float HR2 = fmaxf((A2*A2*HH2 + 2.0f*A2*B2*xyr + B2*B2*y2r) * r_d2 * r_d2, 0.0f);

    float xy3 = p1*p2*HE2 + p1*q2*HR + q1*p2*HT + q1*q2*TR;
    float A3 = 1.0f + 2.0f * xy3 + HR2, B3 = 1.0f - HT2;
    float r_d3 = RCP(fmaxf(1.0f + 2.0f * xy3 + HT2 * HR2, MIN_NORM));
    float al = (A3 * p1 + B3 * p2) * r_d3;
    float be = A3 * q1 * r_d3;
    float ga = B3 * q2 * r_d3;
    float R2 = fmaxf((A3*A3*HT2 + 2.0f*A3*B3*xy3 + B3*B3*HR2) * r_d3 * r_d3, 0.0f);

    float R2g = fmaxf(R2, 1e-30f);
    float rNr = RSQ(R2g);
    float Nr  = R2g * rNr;
    const float maxn = 1.0f - 1e-3f;
    if (Nr > maxn) {
        float s = maxn * rNr;
        al *= s; be *= s; ga *= s;
        R2 = maxn * maxn;
    }

    float dhr = a * (al * HE2 + be * HT + ga * HR);
    float xy4 = -dhr;
    float A4 = 1.0f + 2.0f * xy4 + R2, B4 = 1.0f - HH2;
    float r_d4 = RCP(fmaxf(1.0f + 2.0f * xy4 + HH2 * R2, MIN_NORM));
    float sh = (-A4 * a + B4 * al) * r_d4;
    float st = B4 * be * r_d4;
    float sr = B4 * ga * r_d4;
    float SUB2 = fmaxf((A4*A4*HH2 + 2.0f*A4*B4*xy4 + B4*B4*R2) * r_d4 * r_d4, 0.0f);

    float SUB2g = fmaxf(SUB2, 1e-30f);
    float rNsub = RSQ(SUB2g);
    float Nsub  = SUB2g * rNsub;
    float k = mterm * fast_atanh(fminf(Nsub, 1.0f - 1e-5f)) * rNsub;

    float kh = k * sh;
    float kt = k * st + ricci_k;
    float kr = k * sr + ricci_k;

    float ox = fmaxf(kh*hex + kt*tex + kr*rex, 0.0f);
    float oy = fmaxf(kh*hey + kt*tey + kr*rey, 0.0f);
    float oz = fmaxf(kh*hez + kt*tez + kr*rez, 0.0f);
    float ow = fmaxf(kh*hew + kt*tew + kr*rew, 0.0f);

    if (active) {
        float* dst = sums + (size_t)h * D + sub;
        atomicAdd(dst +  0, ox);   // each instruction: contiguous 64B per edge
        atomicAdd(dst + 16, oy);
        atomicAdd(dst + 32, oz);
        atomicAdd(dst + 48, ow);
        if (sub == 0) atomicAdd(&cnt[h], 1.0f);
    }
}

// ---------------- per-entity finalize: mean -> l2norm -> residual ----------------

__global__ __launch_bounds__(256) void finalize_hop_kernel(
    const float* __restrict__ sums, const float* __restrict__ cnt,
    const float* __restrict__ prev_res,
    float* __restrict__ ent_out, float* __restrict__ res_out, int n_ent)
{
    int row = blockIdx.x * 16 + (threadIdx.x >> 4);
    if (row >= n_ent) return;
    int sub = threadIdx.x & 15;

    float rc = RCP(fmaxf(cnt[row], 1.0f));
    float4 m = ((const float4*)(sums + (size_t)row * D))[sub];
    m.x *= rc; m.y *= rc; m.z *= rc; m.w *= rc;

    float M2 = row16_sum(m.x*m.x + m.y*m.y + m.z*m.z + m.w*m.w);
    float rn = RSQ(fmaxf(M2, 1e-24f));
    float4 v = make_float4(m.x*rn, m.y*rn, m.z*rn, m.w*rn);

    ((float4*)(ent_out + (size_t)row * D))[sub] = v;
    float4 p = ((const float4*)(prev_res + (size_t)row * D))[sub];
    ((float4*)(res_out + (size_t)row * D))[sub] =
        make_float4(0.5f*p.x + v.x, 0.5f*p.y + v.y, 0.5f*p.z + v.z, 0.5f*p.w + v.w);
}

// ---------------- concat ----------------

__global__ void concat_init_kernel(const float4* __restrict__ u,
                                   const float4* __restrict__ res,
                                   float4* __restrict__ bufA,
                                   float4* __restrict__ out,
                                   int user4, int total4)
{
    int i = blockIdx.x * blockDim.x + threadIdx.x;
    if (i >= total4) return;
    float4 v = (i < user4) ? u[i] : res[i - user4];
    bufA[i] = v;
    out[i] = v;
}

// ---------------- CSR build: histogram -> scan -> scatter ----------------

__global__ void hist_kernel(const int* __restrict__ row, int* __restrict__ counts, int nnz)
{
    int i = blockIdx.x * blockDim.x + threadIdx.x;
    if (i < nnz) atomicAdd(&counts[row[i]], 1);
}

// single block of 1024 threads; counts aliases `cursor` (read-before-write per slot)
__global__ __launch_bounds__(1024) void scan_kernel(
    int* __restrict__ counts, int* __restrict__ row_ptr, int* __restrict__ cursor, int n)
{
    __shared__ int lds[1024];
    int tid = threadIdx.x;
    int chunk = (n + 1023) >> 10;
    int lo = tid * chunk;
    int hi = min(lo + chunk, n);

    int s = 0;
    for (int i = lo; i < hi; ++i) s += counts[i];
    lds[tid] = s;
    __syncthreads();
    for (int off = 1; off < 1024; off <<= 1) {
        int t = (tid >= off) ? lds[tid - off] : 0;
        __syncthreads();
        lds[tid] += t;
        __syncthreads();
    }
    int run = lds[tid] - s;   // exclusive start of this chunk
    for (int i = lo; i < hi; ++i) {
        int ci = counts[i];
        row_ptr[i] = run;
        cursor[i] = run;
        run += ci;
    }
    if (tid == 1023) row_ptr[n] = lds[1023];
}

__global__ void scatter_kernel(const int* __restrict__ row, const int* __restrict__ col,
                               const float* __restrict__ val,
                               int* __restrict__ cursor, int2* __restrict__ pair, int nnz)
{
    int i = blockIdx.x * blockDim.x + threadIdx.x;
    if (i >= nnz) return;
    int pos = atomicAdd(&cursor[row[i]], 1);
    pair[pos] = make_int2(col[i], __float_as_int(val[i]));
}

// ---------------- gather SpMM: wave per row, no atomics, fused out += ----

__global__ __launch_bounds__(256) void spmm_csr_kernel(
    const int* __restrict__ row_ptr, const int2* __restrict__ pair,
    const float* __restrict__ cur, float* __restrict__ nxt,
    float* __restrict__ out, int n_rows)
{
    int row = blockIdx.x * 4 + (threadIdx.x >> 6);
    if (row >= n_rows) return;
    int lane = threadIdx.x & 63;

    int s = row_ptr[row];
    int e = row_ptr[row + 1];
    float acc = 0.0f;
    for (int i = s; i < e; ++i) {
        int2 p = pair[i];
        acc = fmaf(__int_as_float(p.y), cur[(size_t)p.x * D + lane], acc);
    }
    size_t idx = (size_t)row * D + lane;
    nxt[idx] = acc;
    out[idx] += acc;
}

// ---------------- launch ----------------

extern "C" void kernel_launch(void* const* d_in, const int* in_sizes, int n_in,
                              void* d_out, int out_size, void* d_ws, size_t ws_size,
                              hipStream_t stream)
{
    const float* uE      = (const float*)d_in[0];
    const float* eE      = (const float*)d_in[1];
    const float* rE      = (const float*)d_in[2];
    const float* adj_val = (const float*)d_in[3];
    const int*   e_head  = (const int*)d_in[4];
    const int*   e_tail  = (const int*)d_in[5];
    const int*   e_type  = (const int*)d_in[6];
    const int*   a_row   = (const int*)d_in[7];
    const int*   a_col   = (const int*)d_in[8];

    const int n_user  = in_sizes[0] / D;   // 100000
    const int n_ent   = in_sizes[1] / D;   // 200000
    const int nnz     = in_sizes[3];       // 2000000
    const int n_edges = in_sizes[4];       // 500000
    const int n_rows  = out_size / D;      // 150000

    float* ws = (float*)d_ws;
    const size_t entElems = (size_t)n_ent * D;           // 12.8M floats
    float* sums    = ws;                                  // later: GCN bufA
    float* cnt     = ws + entElems;
    float* ent1    = ws + entElems + n_ent;               // later: GCN bufB
    float* ent_res = ws + 2 * entElems + n_ent;           // later: CSR arrays

    // CSR arrays overlap dead ent_res region (built after concat_init)
    int*  row_ptr = (int*)ent_res;                        // n_rows+1
    int*  cursor  = row_ptr + (n_rows + 1);               // n_rows+1
    int2* pair    = (int2*)(cursor + n_rows + 1);         // nnz (8B each)

    float* out = (float*)d_out;

    const int edge_blocks = (n_edges + 15) / 16;
    const int ent_blocks  = (n_ent + 15) / 16;

    // ---- RGAT hop 1 ----
    hipMemsetAsync(sums, 0, (entElems + n_ent) * sizeof(float), stream);
    rgat_edge_kernel<<<edge_blocks, 256, 0, stream>>>(eE, rE, e_head, e_tail, e_type,
                                                      sums, cnt, n_edges);
    finalize_hop_kernel<<<ent_blocks, 256, 0, stream>>>(sums, cnt, eE, ent1, ent_res, n_ent);

    // ---- RGAT hop 2 ----
    hipMemsetAsync(sums, 0, (entElems + n_ent) * sizeof(float), stream);
    rgat_edge_kernel<<<edge_blocks, 256, 0, stream>>>(ent1, rE, e_head, e_tail, e_type,
                                                      sums, cnt, n_edges);
    finalize_hop_kernel<<<ent_blocks, 256, 0, stream>>>(sums, cnt, ent_res, ent1, ent_res, n_ent);

    // ---- GCN ----
    float* bufA = sums;
    float* bufB = ent1;

    const int total4 = n_rows * (D / 4);
    const int user4  = n_user * (D / 4);

    // embeds -> bufA and out (ent_res consumed here; its region then reused for CSR)
    concat_init_kernel<<<(total4 + 255) / 256, 256, 0, stream>>>(
        (const float4*)uE, (const float4*)ent_res, (float4*)bufA, (float4*)out,
        user4, total4);

    // build CSR of adj (reused by both layers)
    hipMemsetAsync(cursor, 0, (size_t)(n_rows + 1) * sizeof(int), stream);
    hist_kernel<<<(nnz + 255) / 256, 256, 0, stream>>>(a_row, cursor, nnz);
    scan_kernel<<<1, 1024, 0, stream>>>(cursor, row_ptr, cursor, n_rows);
    scatter_kernel<<<(nnz + 255) / 256, 256, 0, stream>>>(a_row, a_col, adj_val,
                                                          cursor, pair, nnz);

    const int row_blocks = (n_rows + 3) / 4;
    // layer 1: bufB = A*bufA; out += bufB
    spmm_csr_kernel<<<row_blocks, 256, 0, stream>>>(row_ptr, pair, bufA, bufB, out, n_rows);
    // layer 2: bufA = A*bufB; out += bufA
    spmm_csr_kernel<<<row_blocks, 256, 0, stream>>>(row_ptr, pair, bufB, bufA, out, n_rows);
}

// Round 6
// 1076.433 us; speedup vs baseline: 4.2063x; 1.2990x over previous
//
#include <hip/hip_runtime.h>
#include <math.h>

#define D 64
#define MIN_NORM 1e-15f

#define RCP(x)  __builtin_amdgcn_rcpf(x)
#define RSQ(x)  __builtin_amdgcn_rsqf(x)

// ---------------- DPP butterfly within 16-lane rows ----------------
template <int CTRL>
__device__ __forceinline__ float dpp_sum_step(float v) {
    int iv = __builtin_bit_cast(int, v);
    int sh = __builtin_amdgcn_update_dpp(0, iv, CTRL, 0xf, 0xf, true);
    return v + __builtin_bit_cast(float, sh);
}
#define DPP_XOR1  0xB1   // quad_perm [1,0,3,2]
#define DPP_XOR2  0x4E   // quad_perm [2,3,0,1]
#define DPP_HMIR  0x141  // row_half_mirror
#define DPP_MIR   0x140  // row_mirror

__device__ __forceinline__ float row16_sum(float v) {
    v = dpp_sum_step<DPP_XOR1>(v);
    v = dpp_sum_step<DPP_XOR2>(v);
    v = dpp_sum_step<DPP_HMIR>(v);
    v = dpp_sum_step<DPP_MIR>(v);
    return v;
}

// ---------------- fast transcendentals (args >= 0) ----------------

__device__ __forceinline__ float fast_tanh_pos(float x) {
    float t = __expf(-2.0f * x);
    return (1.0f - t) * RCP(1.0f + t);
}

__device__ __forceinline__ float fast_atanh(float x) {
    return 0.5f * __logf((1.0f + x) * RCP(1.0f - x));
}

// ---------------- RGAT edge kernel: 16 lanes/edge, STRIDED dim layout ------
// dim = c*16 + sub. Loads and atomic stores are one full contiguous 64B
// cacheline per instruction per edge. No transpose, no write inflation.

__global__ __launch_bounds__(256) void rgat_edge_kernel(
    const float* __restrict__ ent, const float* __restrict__ rel,
    const int* __restrict__ head, const int* __restrict__ tail,
    const int* __restrict__ etype,
    float* __restrict__ sums, float* __restrict__ cnt, int n_edges)
{
    int e = blockIdx.x * 16 + (threadIdx.x >> 4);
    int ec = min(e, n_edges - 1);          // clamp; no early return (DPP below)
    bool active = (e < n_edges);
    int sub = threadIdx.x & 15;

    int h = head[ec];
    int t = tail[ec];
    int r = etype[ec] - 1;

    const float* hp = ent + (size_t)h * D + sub;
    const float* tp = ent + (size_t)t * D + sub;
    const float* rp = rel + (size_t)r * D + sub;
    float hex = hp[0], hey = hp[16], hez = hp[32], hew = hp[48];
    float tex = tp[0], tey = tp[16], tez = tp[32], tew = tp[48];
    float rex = rp[0], rey = rp[16], rez = rp[32], rew = rp[48];

    float v0 = hex*hex + hey*hey + hez*hez + hew*hew;
    float v1 = tex*tex + tey*tey + tez*tez + tew*tew;
    float v2 = rex*rex + rey*rey + rez*rez + rew*rew;
    float v3 = hex*tex + hey*tey + hez*tez + hew*tew;
    float v4 = hex*rex + hey*rey + hez*rez + hew*rew;
    float v5 = tex*rex + tey*rey + tez*rez + tew*rew;
    float HE2 = row16_sum(v0);
    float TE2 = row16_sum(v1);
    float RE2 = row16_sum(v2);
    float HT  = row16_sum(v3);
    float HR  = row16_sum(v4);
    float TR  = row16_sum(v5);

    // ---- scalar chain (uniform within each 16-lane group) ----
    float S2 = TE2 + 2.0f * TR + RE2;
    float ricci_k = 1e-7f * RSQ(fmaxf(S2, 1e-24f));

    float HE2g = fmaxf(HE2, 1e-30f);
    float rNhe = RSQ(HE2g);
    float Nhe  = HE2g * rNhe;
    float a = fast_tanh_pos(Nhe) * rNhe;
    float HH2 = a * a * HE2;
    float mterm = fmaxf(1.0f - HH2, MIN_NORM);   // = 2/lam
    float rmterm = RCP(mterm);

    float TE2g = fmaxf(TE2, 1e-30f);
    float rNte = RSQ(TE2g);
    float b = fast_tanh_pos(TE2g * rNte * rmterm) * rNte;
    float RE2g = fmaxf(RE2, 1e-30f);
    float rNre = RSQ(RE2g);
    float c = fast_tanh_pos(RE2g * rNre * rmterm) * rNre;

    float y2t = b * b * TE2, xyt = a * b * HT;
    float A1 = 1.0f + 2.0f * xyt + y2t, B1 = 1.0f - HH2;
    float r_d1 = RCP(fmaxf(1.0f + 2.0f * xyt + HH2 * y2t, MIN_NORM));
    float p1 = A1 * a * r_d1, q1 = B1 * b * r_d1;
    float HT2 = fmaxf((A1*A1*HH2 + 2.0f*A1*B1*xyt + B1*B1*y2t) * r_d1 * r_d1, 0.0f);

    float y2r = c * c * RE2, xyr = a * c * HR;
    float A2 = 1.0f + 2.0f * xyr + y2r, B2 = 1.0f - HH2;
    float r_d2 = RCP(fmaxf(1.0f + 2.0f * xyr + HH2 * y2r, MIN_NORM));
    float p2 = A2 * a * r_d2, q2 = B2 * c * r_d2;
    float HR2 = fmaxf((A2*A2*HH2 + 2.0f*A2*B2*xyr + B2*B2*y2r) * r_d2 * r_d2, 0.0f);

    float xy3 = p1*p2*HE2 + p1*q2*HR + q1*p2*HT + q1*q2*TR;
    float A3 = 1.0f + 2.0f * xy3 + HR2, B3 = 1.0f - HT2;
    float r_d3 = RCP(fmaxf(1.0f + 2.0f * xy3 + HT2 * HR2, MIN_NORM));
    float al = (A3 * p1 + B3 * p2) * r_d3;
    float be = A3 * q1 * r_d3;
    float ga = B3 * q2 * r_d3;
    float R2 = fmaxf((A3*A3*HT2 + 2.0f*A3*B3*xy3 + B3*B3*HR2) * r_d3 * r_d3, 0.0f);

    float R2g = fmaxf(R2, 1e-30f);
    float rNr = RSQ(R2g);
    float Nr  = R2g * rNr;
    const float maxn = 1.0f - 1e-3f;
    if (Nr > maxn) {
        float s = maxn * rNr;
        al *= s; be *= s; ga *= s;
        R2 = maxn * maxn;
    }

    float dhr = a * (al * HE2 + be * HT + ga * HR);
    float xy4 = -dhr;
    float A4 = 1.0f + 2.0f * xy4 + R2, B4 = 1.0f - HH2;
    float r_d4 = RCP(fmaxf(1.0f + 2.0f * xy4 + HH2 * R2, MIN_NORM));
    float sh = (-A4 * a + B4 * al) * r_d4;
    float st = B4 * be * r_d4;
    float sr = B4 * ga * r_d4;
    float SUB2 = fmaxf((A4*A4*HH2 + 2.0f*A4*B4*xy4 + B4*B4*R2) * r_d4 * r_d4, 0.0f);

    float SUB2g = fmaxf(SUB2, 1e-30f);
    float rNsub = RSQ(SUB2g);
    float Nsub  = SUB2g * rNsub;
    float k = mterm * fast_atanh(fminf(Nsub, 1.0f - 1e-5f)) * rNsub;

    float kh = k * sh;
    float kt = k * st + ricci_k;
    float kr = k * sr + ricci_k;

    float ox = fmaxf(kh*hex + kt*tex + kr*rex, 0.0f);
    float oy = fmaxf(kh*hey + kt*tey + kr*rey, 0.0f);
    float oz = fmaxf(kh*hez + kt*tez + kr*rez, 0.0f);
    float ow = fmaxf(kh*hew + kt*tew + kr*rew, 0.0f);

    if (active) {
        float* dst = sums + (size_t)h * D + sub;
        atomicAdd(dst +  0, ox);
        atomicAdd(dst + 16, oy);
        atomicAdd(dst + 32, oz);
        atomicAdd(dst + 48, ow);
        if (sub == 0) atomicAdd(&cnt[h], 1.0f);
    }
}

// ---------------- per-entity finalize: mean -> l2norm -> residual ----------------

__global__ __launch_bounds__(256) void finalize_hop_kernel(
    const float* __restrict__ sums, const float* __restrict__ cnt,
    const float* __restrict__ prev_res,
    float* __restrict__ ent_out, float* __restrict__ res_out, int n_ent)
{
    int row = blockIdx.x * 16 + (threadIdx.x >> 4);
    if (row >= n_ent) return;
    int sub = threadIdx.x & 15;

    float rc = RCP(fmaxf(cnt[row], 1.0f));
    float4 m = ((const float4*)(sums + (size_t)row * D))[sub];
    m.x *= rc; m.y *= rc; m.z *= rc; m.w *= rc;

    float M2 = row16_sum(m.x*m.x + m.y*m.y + m.z*m.z + m.w*m.w);
    float rn = RSQ(fmaxf(M2, 1e-24f));
    float4 v = make_float4(m.x*rn, m.y*rn, m.z*rn, m.w*rn);

    ((float4*)(ent_out + (size_t)row * D))[sub] = v;
    float4 p = ((const float4*)(prev_res + (size_t)row * D))[sub];
    ((float4*)(res_out + (size_t)row * D))[sub] =
        make_float4(0.5f*p.x + v.x, 0.5f*p.y + v.y, 0.5f*p.z + v.z, 0.5f*p.w + v.w);
}

// ---------------- concat ----------------

__global__ void concat_init_kernel(const float4* __restrict__ u,
                                   const float4* __restrict__ res,
                                   float4* __restrict__ bufA,
                                   float4* __restrict__ out,
                                   int user4, int total4)
{
    int i = blockIdx.x * blockDim.x + threadIdx.x;
    if (i >= total4) return;
    float4 v = (i < user4) ? u[i] : res[i - user4];
    bufA[i] = v;
    out[i] = v;
}

// ---------------- CSR build: histogram -> 3-phase scan -> scatter ----------------

__global__ void hist_kernel(const int* __restrict__ row, int* __restrict__ counts, int nnz)
{
    int i = blockIdx.x * blockDim.x + threadIdx.x;
    if (i < nnz) atomicAdd(&counts[row[i]], 1);
}

// phase 1: per-block (1024 elems) local exclusive scan + block total
__global__ __launch_bounds__(256) void block_scan_kernel(
    const int* __restrict__ counts, int* __restrict__ local_scan,
    int* __restrict__ block_sums, int n)
{
    __shared__ int wsum[4];
    int tid  = threadIdx.x;
    int lane = tid & 63;
    int wave = tid >> 6;
    int base = blockIdx.x * 1024 + tid * 4;

    int4 v = make_int4(0, 0, 0, 0);
    if (base + 3 < n) {
        v = *(const int4*)(counts + base);
    } else {
        if (base + 0 < n) v.x = counts[base + 0];
        if (base + 1 < n) v.y = counts[base + 1];
        if (base + 2 < n) v.z = counts[base + 2];
        if (base + 3 < n) v.w = counts[base + 3];
    }
    int total = v.x + v.y + v.z + v.w;

    // inclusive scan of per-thread totals within the wave
    int incl = total;
#pragma unroll
    for (int off = 1; off < 64; off <<= 1) {
        int u = __shfl_up(incl, off, 64);
        if (lane >= off) incl += u;
    }
    if (lane == 63) wsum[wave] = incl;
    __syncthreads();
    int woff = 0;
    for (int w = 0; w < wave; ++w) woff += wsum[w];
    int excl = woff + incl - total;

    if (tid == 255) block_sums[blockIdx.x] = woff + incl;  // block grand total

    int p0 = excl;
    int p1 = p0 + v.x;
    int p2 = p1 + v.y;
    int p3 = p2 + v.z;
    if (base + 3 < n) {
        *(int4*)(local_scan + base) = make_int4(p0, p1, p2, p3);
    } else {
        if (base + 0 < n) local_scan[base + 0] = p0;
        if (base + 1 < n) local_scan[base + 1] = p1;
        if (base + 2 < n) local_scan[base + 2] = p2;
        if (base + 3 < n) local_scan[base + 3] = p3;
    }
}

// phase 2: single block scans block totals (nb <= 256) -> exclusive offsets
__global__ __launch_bounds__(256) void scan_blocksums_kernel(
    const int* __restrict__ block_sums, int* __restrict__ block_offs,
    int* __restrict__ row_ptr, int n, int nb)
{
    __shared__ int lds[256];
    int tid = threadIdx.x;
    int v = (tid < nb) ? block_sums[tid] : 0;
    lds[tid] = v;
    __syncthreads();
    for (int off = 1; off < 256; off <<= 1) {
        int t = (tid >= off) ? lds[tid - off] : 0;
        __syncthreads();
        lds[tid] += t;
        __syncthreads();
    }
    block_offs[tid] = lds[tid] - v;          // exclusive
    if (tid == nb - 1) row_ptr[n] = lds[tid]; // grand total
}

// phase 3: add block offsets, materialize row_ptr + cursor
__global__ void apply_offsets_kernel(const int* __restrict__ local_scan,
                                     const int* __restrict__ block_offs,
                                     int* __restrict__ row_ptr,
                                     int* __restrict__ cursor, int n)
{
    int i = blockIdx.x * blockDim.x + threadIdx.x;
    if (i >= n) return;
    int v = local_scan[i] + block_offs[i >> 10];
    row_ptr[i] = v;
    cursor[i]  = v;
}

__global__ void scatter_kernel(const int* __restrict__ row, const int* __restrict__ col,
                               const float* __restrict__ val,
                               int* __restrict__ cursor, int2* __restrict__ pair, int nnz)
{
    int i = blockIdx.x * blockDim.x + threadIdx.x;
    if (i >= nnz) return;
    int pos = atomicAdd(&cursor[row[i]], 1);
    pair[pos] = make_int2(col[i], __float_as_int(val[i]));
}

// ---------------- gather SpMM: wave per row, no atomics, fused out += ----

__global__ __launch_bounds__(256) void spmm_csr_kernel(
    const int* __restrict__ row_ptr, const int2* __restrict__ pair,
    const float* __restrict__ cur, float* __restrict__ nxt,
    float* __restrict__ out, int n_rows)
{
    int row = blockIdx.x * 4 + (threadIdx.x >> 6);
    if (row >= n_rows) return;
    int lane = threadIdx.x & 63;

    int s = row_ptr[row];
    int e = row_ptr[row + 1];
    float acc = 0.0f;
    for (int i = s; i < e; ++i) {
        int2 p = pair[i];
        acc = fmaf(__int_as_float(p.y), cur[(size_t)p.x * D + lane], acc);
    }
    size_t idx = (size_t)row * D + lane;
    nxt[idx] = acc;
    out[idx] += acc;
}

// ---------------- launch ----------------

extern "C" void kernel_launch(void* const* d_in, const int* in_sizes, int n_in,
                              void* d_out, int out_size, void* d_ws, size_t ws_size,
                              hipStream_t stream)
{
    const float* uE      = (const float*)d_in[0];
    const float* eE      = (const float*)d_in[1];
    const float* rE      = (const float*)d_in[2];
    const float* adj_val = (const float*)d_in[3];
    const int*   e_head  = (const int*)d_in[4];
    const int*   e_tail  = (const int*)d_in[5];
    const int*   e_type  = (const int*)d_in[6];
    const int*   a_row   = (const int*)d_in[7];
    const int*   a_col   = (const int*)d_in[8];

    const int n_user  = in_sizes[0] / D;   // 100000
    const int n_ent   = in_sizes[1] / D;   // 200000
    const int nnz     = in_sizes[3];       // 2000000
    const int n_edges = in_sizes[4];       // 500000
    const int n_rows  = out_size / D;      // 150000

    float* ws = (float*)d_ws;
    const size_t entElems = (size_t)n_ent * D;           // 12.8M floats
    float* sums    = ws;                                  // later: GCN bufA
    float* cnt     = ws + entElems;
    float* ent1    = ws + entElems + n_ent;               // later: GCN bufB
    float* ent_res = ws + 2 * entElems + n_ent;           // later: CSR arrays

    // CSR + scan scratch overlap dead ent_res region (12.8M ints available)
    int*  row_ptr    = (int*)ent_res;                     // n_rows+1
    int*  cursor     = row_ptr + (n_rows + 1);            // n_rows+1 (aliases counts)
    int2* pair       = (int2*)(cursor + n_rows + 1);      // nnz (8B each)
    int*  local_scan = (int*)(pair + nnz);                // n_rows (int4-aligned)
    int*  block_sums = local_scan + n_rows + 4;           // <=256
    int*  block_offs = block_sums + 256;                  // 256

    float* out = (float*)d_out;

    const int edge_blocks = (n_edges + 15) / 16;
    const int ent_blocks  = (n_ent + 15) / 16;

    // ---- RGAT hop 1 ----
    hipMemsetAsync(sums, 0, (entElems + n_ent) * sizeof(float), stream);
    rgat_edge_kernel<<<edge_blocks, 256, 0, stream>>>(eE, rE, e_head, e_tail, e_type,
                                                      sums, cnt, n_edges);
    finalize_hop_kernel<<<ent_blocks, 256, 0, stream>>>(sums, cnt, eE, ent1, ent_res, n_ent);

    // ---- RGAT hop 2 ----
    hipMemsetAsync(sums, 0, (entElems + n_ent) * sizeof(float), stream);
    rgat_edge_kernel<<<edge_blocks, 256, 0, stream>>>(ent1, rE, e_head, e_tail, e_type,
                                                      sums, cnt, n_edges);
    finalize_hop_kernel<<<ent_blocks, 256, 0, stream>>>(sums, cnt, ent_res, ent1, ent_res, n_ent);

    // ---- GCN ----
    float* bufA = sums;
    float* bufB = ent1;

    const int total4 = n_rows * (D / 4);
    const int user4  = n_user * (D / 4);

    concat_init_kernel<<<(total4 + 255) / 256, 256, 0, stream>>>(
        (const float4*)uE, (const float4*)ent_res, (float4*)bufA, (float4*)out,
        user4, total4);

    // build CSR of adj (reused by both layers)
    const int nb = (n_rows + 1023) / 1024;   // 147 (<=256)
    hipMemsetAsync(cursor, 0, (size_t)(n_rows + 1) * sizeof(int), stream);
    hist_kernel<<<(nnz + 255) / 256, 256, 0, stream>>>(a_row, cursor, nnz);
    block_scan_kernel<<<nb, 256, 0, stream>>>(cursor, local_scan, block_sums, n_rows);
    scan_blocksums_kernel<<<1, 256, 0, stream>>>(block_sums, block_offs, row_ptr, n_rows, nb);
    apply_offsets_kernel<<<(n_rows + 255) / 256, 256, 0, stream>>>(local_scan, block_offs,
                                                                   row_ptr, cursor, n_rows);
    scatter_kernel<<<(nnz + 255) / 256, 256, 0, stream>>>(a_row, a_col, adj_val,
                                                          cursor, pair, nnz);

    const int row_blocks = (n_rows + 3) / 4;
    // layer 1: bufB = A*bufA; out += bufB
    spmm_csr_kernel<<<row_blocks, 256, 0, stream>>>(row_ptr, pair, bufA, bufB, out, n_rows);
    // layer 2: bufA = A*bufB; out += bufA
    spmm_csr_kernel<<<row_blocks, 256, 0, stream>>>(row_ptr, pair, bufB, bufA, out, n_rows);
}

// Round 7
// 903.125 us; speedup vs baseline: 5.0134x; 1.1919x over previous
//
#include <hip/hip_runtime.h>
#include <math.h>

#define D 64
#define MIN_NORM 1e-15f

#define RCP(x)  __builtin_amdgcn_rcpf(x)
#define RSQ(x)  __builtin_amdgcn_rsqf(x)

// ---------------- DPP butterfly within 16-lane rows ----------------
template <int CTRL>
__device__ __forceinline__ float dpp_sum_step(float v) {
    int iv = __builtin_bit_cast(int, v);
    int sh = __builtin_amdgcn_update_dpp(0, iv, CTRL, 0xf, 0xf, true);
    return v + __builtin_bit_cast(float, sh);
}
#define DPP_XOR1  0xB1   // quad_perm [1,0,3,2]
#define DPP_XOR2  0x4E   // quad_perm [2,3,0,1]
#define DPP_HMIR  0x141  // row_half_mirror
#define DPP_MIR   0x140  // row_mirror

__device__ __forceinline__ float row16_sum(float v) {
    v = dpp_sum_step<DPP_XOR1>(v);
    v = dpp_sum_step<DPP_XOR2>(v);
    v = dpp_sum_step<DPP_HMIR>(v);
    v = dpp_sum_step<DPP_MIR>(v);
    return v;
}

// ---------------- fast transcendentals (args >= 0) ----------------

__device__ __forceinline__ float fast_tanh_pos(float x) {
    float t = __expf(-2.0f * x);
    return (1.0f - t) * RCP(1.0f + t);
}

__device__ __forceinline__ float fast_atanh(float x) {
    return 0.5f * __logf((1.0f + x) * RCP(1.0f - x));
}

// ---------------- RGAT edge kernel: 16 lanes/edge, STRIDED dim layout ------
// dim = c*16 + sub. Loads and atomic stores are one full contiguous 64B
// cacheline per instruction per edge. No transpose, no write inflation.

__global__ __launch_bounds__(256) void rgat_edge_kernel(
    const float* __restrict__ ent, const float* __restrict__ rel,
    const int* __restrict__ head, const int* __restrict__ tail,
    const int* __restrict__ etype,
    float* __restrict__ sums, float* __restrict__ cnt, int n_edges)
{
    int e = blockIdx.x * 16 + (threadIdx.x >> 4);
    int ec = min(e, n_edges - 1);          // clamp; no early return (DPP below)
    bool active = (e < n_edges);
    int sub = threadIdx.x & 15;

    int h = head[ec];
    int t = tail[ec];
    int r = etype[ec] - 1;

    const float* hp = ent + (size_t)h * D + sub;
    const float* tp = ent + (size_t)t * D + sub;
    const float* rp = rel + (size_t)r * D + sub;
    float hex = hp[0], hey = hp[16], hez = hp[32], hew = hp[48];
    float tex = tp[0], tey = tp[16], tez = tp[32], tew = tp[48];
    float rex = rp[0], rey = rp[16], rez = rp[32], rew = rp[48];

    float v0 = hex*hex + hey*hey + hez*hez + hew*hew;
    float v1 = tex*tex + tey*tey + tez*tez + tew*tew;
    float v2 = rex*rex + rey*rey + rez*rez + rew*rew;
    float v3 = hex*tex + hey*tey + hez*tez + hew*tew;
    float v4 = hex*rex + hey*rey + hez*rez + hew*rew;
    float v5 = tex*rex + tey*rey + tez*rez + tew*rew;
    float HE2 = row16_sum(v0);
    float TE2 = row16_sum(v1);
    float RE2 = row16_sum(v2);
    float HT  = row16_sum(v3);
    float HR  = row16_sum(v4);
    float TR  = row16_sum(v5);

    // ---- scalar chain (uniform within each 16-lane group) ----
    float S2 = TE2 + 2.0f * TR + RE2;
    float ricci_k = 1e-7f * RSQ(fmaxf(S2, 1e-24f));

    float HE2g = fmaxf(HE2, 1e-30f);
    float rNhe = RSQ(HE2g);
    float Nhe  = HE2g * rNhe;
    float a = fast_tanh_pos(Nhe) * rNhe;
    float HH2 = a * a * HE2;
    float mterm = fmaxf(1.0f - HH2, MIN_NORM);   // = 2/lam
    float rmterm = RCP(mterm);

    float TE2g = fmaxf(TE2, 1e-30f);
    float rNte = RSQ(TE2g);
    float b = fast_tanh_pos(TE2g * rNte * rmterm) * rNte;
    float RE2g = fmaxf(RE2, 1e-30f);
    float rNre = RSQ(RE2g);
    float c = fast_tanh_pos(RE2g * rNre * rmterm) * rNre;

    float y2t = b * b * TE2, xyt = a * b * HT;
    float A1 = 1.0f + 2.0f * xyt + y2t, B1 = 1.0f - HH2;
    float r_d1 = RCP(fmaxf(1.0f + 2.0f * xyt + HH2 * y2t, MIN_NORM));
    float p1 = A1 * a * r_d1, q1 = B1 * b * r_d1;
    float HT2 = fmaxf((A1*A1*HH2 + 2.0f*A1*B1*xyt + B1*B1*y2t) * r_d1 * r_d1, 0.0f);

    float y2r = c * c * RE2, xyr = a * c * HR;
    float A2 = 1.0f + 2.0f * xyr + y2r, B2 = 1.0f - HH2;
    float r_d2 = RCP(fmaxf(1.0f + 2.0f * xyr + HH2 * y2r, MIN_NORM));
    float p2 = A2 * a * r_d2, q2 = B2 * c * r_d2;
    float HR2 = fmaxf((A2*A2*HH2 + 2.0f*A2*B2*xyr + B2*B2*y2r) * r_d2 * r_d2, 0.0f);

    float xy3 = p1*p2*HE2 + p1*q2*HR + q1*p2*HT + q1*q2*TR;
    float A3 = 1.0f + 2.0f * xy3 + HR2, B3 = 1.0f - HT2;
    float r_d3 = RCP(fmaxf(1.0f + 2.0f * xy3 + HT2 * HR2, MIN_NORM));
    float al = (A3 * p1 + B3 * p2) * r_d3;
    float be = A3 * q1 * r_d3;
    float ga = B3 * q2 * r_d3;
    float R2 = fmaxf((A3*A3*HT2 + 2.0f*A3*B3*xy3 + B3*B3*HR2) * r_d3 * r_d3, 0.0f);

    float R2g = fmaxf(R2, 1e-30f);
    float rNr = RSQ(R2g);
    float Nr  = R2g * rNr;
    const float maxn = 1.0f - 1e-3f;
    if (Nr > maxn) {
        float s = maxn * rNr;
        al *= s; be *= s; ga *= s;
        R2 = maxn * maxn;
    }

    float dhr = a * (al * HE2 + be * HT + ga * HR);
    float xy4 = -dhr;
    float A4 = 1.0f + 2.0f * xy4 + R2, B4 = 1.0f - HH2;
    float r_d4 = RCP(fmaxf(1.0f + 2.0f * xy4 + HH2 * R2, MIN_NORM));
    float sh = (-A4 * a + B4 * al) * r_d4;
    float st = B4 * be * r_d4;
    float sr = B4 * ga * r_d4;
    float SUB2 = fmaxf((A4*A4*HH2 + 2.0f*A4*B4*xy4 + B4*B4*R2) * r_d4 * r_d4, 0.0f);

    float SUB2g = fmaxf(SUB2, 1e-30f);
    float rNsub = RSQ(SUB2g);
    float Nsub  = SUB2g * rNsub;
    float k = mterm * fast_atanh(fminf(Nsub, 1.0f - 1e-5f)) * rNsub;

    float kh = k * sh;
    float kt = k * st + ricci_k;
    float kr = k * sr + ricci_k;

    float ox = fmaxf(kh*hex + kt*tex + kr*rex, 0.0f);
    float oy = fmaxf(kh*hey + kt*tey + kr*rey, 0.0f);
    float oz = fmaxf(kh*hez + kt*tez + kr*rez, 0.0f);
    float ow = fmaxf(kh*hew + kt*tew + kr*rew, 0.0f);

    if (active) {
        float* dst = sums + (size_t)h * D + sub;
        atomicAdd(dst +  0, ox);
        atomicAdd(dst + 16, oy);
        atomicAdd(dst + 32, oz);
        atomicAdd(dst + 48, ow);
        if (sub == 0) atomicAdd(&cnt[h], 1.0f);
    }
}

// ---------------- per-entity finalize: mean -> l2norm -> residual ----------------

__global__ __launch_bounds__(256) void finalize_hop_kernel(
    const float* __restrict__ sums, const float* __restrict__ cnt,
    const float* __restrict__ prev_res,
    float* __restrict__ ent_out, float* __restrict__ res_out, int n_ent)
{
    int row = blockIdx.x * 16 + (threadIdx.x >> 4);
    if (row >= n_ent) return;
    int sub = threadIdx.x & 15;

    float rc = RCP(fmaxf(cnt[row], 1.0f));
    float4 m = ((const float4*)(sums + (size_t)row * D))[sub];
    m.x *= rc; m.y *= rc; m.z *= rc; m.w *= rc;

    float M2 = row16_sum(m.x*m.x + m.y*m.y + m.z*m.z + m.w*m.w);
    float rn = RSQ(fmaxf(M2, 1e-24f));
    float4 v = make_float4(m.x*rn, m.y*rn, m.z*rn, m.w*rn);

    ((float4*)(ent_out + (size_t)row * D))[sub] = v;
    float4 p = ((const float4*)(prev_res + (size_t)row * D))[sub];
    ((float4*)(res_out + (size_t)row * D))[sub] =
        make_float4(0.5f*p.x + v.x, 0.5f*p.y + v.y, 0.5f*p.z + v.z, 0.5f*p.w + v.w);
}

// ---------------- concat ----------------

__global__ void concat_init_kernel(const float4* __restrict__ u,
                                   const float4* __restrict__ res,
                                   float4* __restrict__ bufA,
                                   float4* __restrict__ out,
                                   int user4, int total4)
{
    int i = blockIdx.x * blockDim.x + threadIdx.x;
    if (i >= total4) return;
    float4 v = (i < user4) ? u[i] : res[i - user4];
    bufA[i] = v;
    out[i] = v;
}

// ---------------- CSR build: histogram -> 3-phase scan -> scatter ----------------

__global__ void hist_kernel(const int* __restrict__ row, int* __restrict__ counts, int nnz)
{
    int i = blockIdx.x * blockDim.x + threadIdx.x;
    if (i < nnz) atomicAdd(&counts[row[i]], 1);
}

// phase 1: per-block (1024 elems) local exclusive scan + block total
__global__ __launch_bounds__(256) void block_scan_kernel(
    const int* __restrict__ counts, int* __restrict__ local_scan,
    int* __restrict__ block_sums, int n)
{
    __shared__ int wsum[4];
    int tid  = threadIdx.x;
    int lane = tid & 63;
    int wave = tid >> 6;
    int base = blockIdx.x * 1024 + tid * 4;

    int4 v = make_int4(0, 0, 0, 0);
    if (base + 3 < n) {
        v = *(const int4*)(counts + base);
    } else {
        if (base + 0 < n) v.x = counts[base + 0];
        if (base + 1 < n) v.y = counts[base + 1];
        if (base + 2 < n) v.z = counts[base + 2];
        if (base + 3 < n) v.w = counts[base + 3];
    }
    int total = v.x + v.y + v.z + v.w;

    int incl = total;
#pragma unroll
    for (int off = 1; off < 64; off <<= 1) {
        int u = __shfl_up(incl, off, 64);
        if (lane >= off) incl += u;
    }
    if (lane == 63) wsum[wave] = incl;
    __syncthreads();
    int woff = 0;
    for (int w = 0; w < wave; ++w) woff += wsum[w];
    int excl = woff + incl - total;

    if (tid == 255) block_sums[blockIdx.x] = woff + incl;

    int p0 = excl;
    int p1 = p0 + v.x;
    int p2 = p1 + v.y;
    int p3 = p2 + v.z;
    if (base + 3 < n) {
        *(int4*)(local_scan + base) = make_int4(p0, p1, p2, p3);
    } else {
        if (base + 0 < n) local_scan[base + 0] = p0;
        if (base + 1 < n) local_scan[base + 1] = p1;
        if (base + 2 < n) local_scan[base + 2] = p2;
        if (base + 3 < n) local_scan[base + 3] = p3;
    }
}

// phase 2: single block scans block totals (nb <= 256) -> exclusive offsets
__global__ __launch_bounds__(256) void scan_blocksums_kernel(
    const int* __restrict__ block_sums, int* __restrict__ block_offs,
    int* __restrict__ row_ptr, int n, int nb)
{
    __shared__ int lds[256];
    int tid = threadIdx.x;
    int v = (tid < nb) ? block_sums[tid] : 0;
    lds[tid] = v;
    __syncthreads();
    for (int off = 1; off < 256; off <<= 1) {
        int t = (tid >= off) ? lds[tid - off] : 0;
        __syncthreads();
        lds[tid] += t;
        __syncthreads();
    }
    block_offs[tid] = lds[tid] - v;
    if (tid == nb - 1) row_ptr[n] = lds[tid];
}

// phase 3: add block offsets, materialize row_ptr + cursor
__global__ void apply_offsets_kernel(const int* __restrict__ local_scan,
                                     const int* __restrict__ block_offs,
                                     int* __restrict__ row_ptr,
                                     int* __restrict__ cursor, int n)
{
    int i = blockIdx.x * blockDim.x + threadIdx.x;
    if (i >= n) return;
    int v = local_scan[i] + block_offs[i >> 10];
    row_ptr[i] = v;
    cursor[i]  = v;
}

__global__ void scatter_kernel(const int* __restrict__ row, const int* __restrict__ col,
                               const float* __restrict__ val,
                               int* __restrict__ cursor, int2* __restrict__ pair, int nnz)
{
    int i = blockIdx.x * blockDim.x + threadIdx.x;
    if (i >= nnz) return;
    int pos = atomicAdd(&cursor[row[i]], 1);
    pair[pos] = make_int2(col[i], __float_as_int(val[i]));
}

// ---------------- gather SpMM: wave per row, unroll-4 for MLP ----------------

__global__ __launch_bounds__(256) void spmm_csr_kernel(
    const int* __restrict__ row_ptr, const int2* __restrict__ pair,
    const float* __restrict__ cur, float* __restrict__ nxt,
    float* __restrict__ out, int n_rows)
{
    int row = blockIdx.x * 4 + (threadIdx.x >> 6);
    if (row >= n_rows) return;
    int lane = threadIdx.x & 63;

    int s = row_ptr[row];
    int e = row_ptr[row + 1];

    float acc0 = 0.0f, acc1 = 0.0f, acc2 = 0.0f, acc3 = 0.0f;
    int i = s;
    for (; i + 4 <= e; i += 4) {
        int2 p0 = pair[i + 0];
        int2 p1 = pair[i + 1];
        int2 p2 = pair[i + 2];
        int2 p3 = pair[i + 3];
        float x0 = cur[(size_t)p0.x * D + lane];
        float x1 = cur[(size_t)p1.x * D + lane];
        float x2 = cur[(size_t)p2.x * D + lane];
        float x3 = cur[(size_t)p3.x * D + lane];
        acc0 = fmaf(__int_as_float(p0.y), x0, acc0);
        acc1 = fmaf(__int_as_float(p1.y), x1, acc1);
        acc2 = fmaf(__int_as_float(p2.y), x2, acc2);
        acc3 = fmaf(__int_as_float(p3.y), x3, acc3);
    }
    for (; i < e; ++i) {
        int2 p = pair[i];
        acc0 = fmaf(__int_as_float(p.y), cur[(size_t)p.x * D + lane], acc0);
    }
    float acc = (acc0 + acc1) + (acc2 + acc3);

    size_t idx = (size_t)row * D + lane;
    nxt[idx] = acc;
    out[idx] += acc;
}

// ---------------- launch ----------------

extern "C" void kernel_launch(void* const* d_in, const int* in_sizes, int n_in,
                              void* d_out, int out_size, void* d_ws, size_t ws_size,
                              hipStream_t stream)
{
    const float* uE      = (const float*)d_in[0];
    const float* eE      = (const float*)d_in[1];
    const float* rE      = (const float*)d_in[2];
    const float* adj_val = (const float*)d_in[3];
    const int*   e_head  = (const int*)d_in[4];
    const int*   e_tail  = (const int*)d_in[5];
    const int*   e_type  = (const int*)d_in[6];
    const int*   a_row   = (const int*)d_in[7];
    const int*   a_col   = (const int*)d_in[8];

    const int n_user  = in_sizes[0] / D;   // 100000
    const int n_ent   = in_sizes[1] / D;   // 200000
    const int nnz     = in_sizes[3];       // 2000000
    const int n_edges = in_sizes[4];       // 500000
    const int n_rows  = out_size / D;      // 150000

    float* ws = (float*)d_ws;
    const size_t entElems = (size_t)n_ent * D;           // 12.8M floats
    float* sums    = ws;                                  // later: GCN bufA
    float* cnt     = ws + entElems;
    float* ent1    = ws + entElems + n_ent;               // later: GCN bufB
    float* ent_res = ws + 2 * entElems + n_ent;           // later: CSR arrays

    int*  row_ptr    = (int*)ent_res;                     // n_rows+1
    int*  cursor     = row_ptr + (n_rows + 1);            // n_rows+1 (aliases counts)
    int2* pair       = (int2*)(cursor + n_rows + 1);      // nnz (8B each)
    int*  local_scan = (int*)(pair + nnz);                // n_rows (int4-aligned)
    int*  block_sums = local_scan + n_rows + 4;           // <=256
    int*  block_offs = block_sums + 256;                  // 256

    float* out = (float*)d_out;

    const int edge_blocks = (n_edges + 15) / 16;
    const int ent_blocks  = (n_ent + 15) / 16;

    // ---- RGAT hop 1 ----
    hipMemsetAsync(sums, 0, (entElems + n_ent) * sizeof(float), stream);
    rgat_edge_kernel<<<edge_blocks, 256, 0, stream>>>(eE, rE, e_head, e_tail, e_type,
                                                      sums, cnt, n_edges);
    finalize_hop_kernel<<<ent_blocks, 256, 0, stream>>>(sums, cnt, eE, ent1, ent_res, n_ent);

    // ---- RGAT hop 2 ----
    hipMemsetAsync(sums, 0, (entElems + n_ent) * sizeof(float), stream);
    rgat_edge_kernel<<<edge_blocks, 256, 0, stream>>>(ent1, rE, e_head, e_tail, e_type,
                                                      sums, cnt, n_edges);
    finalize_hop_kernel<<<ent_blocks, 256, 0, stream>>>(sums, cnt, ent_res, ent1, ent_res, n_ent);

    // ---- GCN ----
    float* bufA = sums;
    float* bufB = ent1;

    const int total4 = n_rows * (D / 4);
    const int user4  = n_user * (D / 4);

    concat_init_kernel<<<(total4 + 255) / 256, 256, 0, stream>>>(
        (const float4*)uE, (const float4*)ent_res, (float4*)bufA, (float4*)out,
        user4, total4);

    // build CSR of adj (reused by both layers)
    const int nb = (n_rows + 1023) / 1024;   // 147 (<=256)
    hipMemsetAsync(cursor, 0, (size_t)(n_rows + 1) * sizeof(int), stream);
    hist_kernel<<<(nnz + 255) / 256, 256, 0, stream>>>(a_row, cursor, nnz);
    block_scan_kernel<<<nb, 256, 0, stream>>>(cursor, local_scan, block_sums, n_rows);
    scan_blocksums_kernel<<<1, 256, 0, stream>>>(block_sums, block_offs, row_ptr, n_rows, nb);
    apply_offsets_kernel<<<(n_rows + 255) / 256, 256, 0, stream>>>(local_scan, block_offs,
                                                                   row_ptr, cursor, n_rows);
    scatter_kernel<<<(nnz + 255) / 256, 256, 0, stream>>>(a_row, a_col, adj_val,
                                                          cursor, pair, nnz);

    const int row_blocks = (n_rows + 3) / 4;
    // layer 1: bufB = A*bufA; out += bufB
    spmm_csr_kernel<<<row_blocks, 256, 0, stream>>>(row_ptr, pair, bufA, bufB, out, n_rows);
    // layer 2: bufA = A*bufB; out += bufA
    spmm_csr_kernel<<<row_blocks, 256, 0, stream>>>(row_ptr, pair, bufB, bufA, out, n_rows);
}